// Round 7
// baseline (324.135 us; speedup 1.0000x reference)
//
#include <hip/hip_runtime.h>
#include <stdint.h>

typedef unsigned short u16;
typedef float f32x4 __attribute__((ext_vector_type(4)));
typedef _Float16 half8 __attribute__((ext_vector_type(8)));
typedef __fp16 fp16x2 __attribute__((ext_vector_type(2)));

#define B_  8
#define M_  2
#define DK_ 512
#define D_  256
#define N_  2048
#define DV_ 512

#define OUT_FLOATS (B_*N_*DV_)     /* 8388608 */
#define QB_U16     (B_*M_*N_*D_)   /* 8388608 u16 elements = 16 MiB */

// ---- fp16 pack/unpack helpers -------------------------------------------
__device__ __forceinline__ uint32_t pk16(float a, float b){
    fp16x2 h = __builtin_amdgcn_cvt_pkrtz(a, b);      // v_cvt_pkrtz_f16_f32
    return __builtin_bit_cast(uint32_t, h);
}
__device__ __forceinline__ float h2f_lo(uint32_t u){
    return (float)__builtin_bit_cast(_Float16, (unsigned short)(u & 0xffffu));
}
__device__ __forceinline__ float h2f_hi(uint32_t u){
    return (float)__builtin_bit_cast(_Float16, (unsigned short)(u >> 16));
}

// ============================================================
// K0: transpose-convert qt,kt (fp32 [b, m*256+c, i]) -> f16 [ (b*2+m), row, c ]
// staged into the d_out "output" region. Also folds bar-sum (k1).
// ============================================================
__global__ __launch_bounds__(256) void k0_transpose(const float* __restrict__ qt,
                                                    const float* __restrict__ kt,
                                                    u16* __restrict__ dstBase,
                                                    float* __restrict__ wsBar){
    const int it = blockIdx.x, yc = blockIdx.y, z = blockIdx.z;
    const int b = z & 7, src = z >> 3;
    const float* sp = src ? kt : qt;
    u16* dp = dstBase + (size_t)src * QB_U16;
    const int m = yc >> 2;
    const int cbase = (yc & 3) * 64;
    const int i0 = it * 64;
    __shared__ u16 lds[64 * 72];   // [i][c], pad 72 keeps 16B alignment
    const int t = threadIdx.x;
    {
        const int c_loc = t >> 2;
        const int iq = (t & 3) * 16;
        const float* g = sp + (size_t)(b*DK_ + m*D_ + cbase + c_loc) * N_ + i0 + iq;
        float vv[16];
        *(float4*)&vv[0]  = *(const float4*)(g + 0);
        *(float4*)&vv[4]  = *(const float4*)(g + 4);
        *(float4*)&vv[8]  = *(const float4*)(g + 8);
        *(float4*)&vv[12] = *(const float4*)(g + 12);
        #pragma unroll
        for (int e = 0; e < 16; ++e){
            _Float16 hf = (_Float16)vv[e];
            lds[(iq + e)*72 + c_loc] = __builtin_bit_cast(unsigned short, hf);
        }
        if (src == 0){   // folded k1: partial sum over this thread's 16 i
            float s = 0.f;
            #pragma unroll
            for (int e = 0; e < 16; ++e) s += vv[e];
            s += __shfl_xor(s, 1);
            s += __shfl_xor(s, 2);
            if ((t & 3) == 0)
                atomicAdd(&wsBar[b*DK_ + m*D_ + cbase + c_loc], s);
        }
    }
    __syncthreads();
    {
        const int i_loc = t >> 2;
        const int cq = (t & 3) * 16;
        uint4 a  = *(const uint4*)&lds[i_loc*72 + cq];
        uint4 b2 = *(const uint4*)&lds[i_loc*72 + cq + 8];
        u16* o = dp + (size_t)((b*M_ + m)*N_ + i0 + i_loc) * D_ + cbase + cq;
        *(uint4*)o = a;
        *(uint4*)(o + 8) = b2;
    }
}

// ============================================================
// K0v: vt fp32 [b][dv][j] -> vF f16 fragment-tiled:
// vF[b][jc(64)][g(4)][dv(512)][8 f16]  (one 32KB contiguous slab per chunk)
// ============================================================
__global__ __launch_bounds__(256) void k0_vconv(const float* __restrict__ vt,
                                                u16* __restrict__ vF){
    const int idx = blockIdx.x * 256 + threadIdx.x;   // 0 .. 2^20-1
    const int dv = idx & 511;
    const int g  = (idx >> 9) & 3;
    const int jc = (idx >> 11) & 63;
    const int b  = idx >> 17;
    const float* src = vt + ((size_t)(b*DV_ + dv))*N_ + jc*32 + g*8;
    float4 f0 = *(const float4*)src;
    float4 f1 = *(const float4*)(src + 4);
    uint4 o;
    o.x = pk16(f0.x, f0.y);
    o.y = pk16(f0.z, f0.w);
    o.z = pk16(f1.x, f1.y);
    o.w = pk16(f1.z, f1.w);
    *(uint4*)(vF + (size_t)idx * 8) = o;
}

// ============================================================
// K2: logits[b*2+m] = (sum_c weight[m,c] * barSum[b,c]) / N
// ============================================================
__global__ void k2_logits(const float* __restrict__ wgt,
                          const float* __restrict__ bar,
                          float* __restrict__ wsLog){
    const int bm = blockIdx.x;
    const int b = bm >> 1, m = bm & 1;
    const int l = threadIdx.x; // 64
    float s = 0.f;
    #pragma unroll
    for (int k = 0; k < 8; ++k){
        const int c = l + k*64;
        s += wgt[m*DK_ + c] * bar[b*DK_ + c];
    }
    s += __shfl_xor(s, 1); s += __shfl_xor(s, 2); s += __shfl_xor(s, 4);
    s += __shfl_xor(s, 8); s += __shfl_xor(s, 16); s += __shfl_xor(s, 32);
    if (l == 0) wsLog[bm] = s * (1.f / (float)N_);
}

// ============================================================
// K3: S = q·k for both mixtures, E = exp(S/sqrt(512)) packed as f16 pair
// (m0 lo, m1 hi) into the dword that will later hold attn[b,i,j] fp32.
// Epilogue accumulates per-row exp-sums into wsSum via atomics.
// ============================================================
__global__ __launch_bounds__(256, 2) void k3_qk(const u16* __restrict__ qB,
                                                const u16* __restrict__ kB,
                                                uint32_t* __restrict__ attnE,
                                                float* __restrict__ wsSum){
    const int jt = blockIdx.x, it = blockIdx.y, b = blockIdx.z;
    const int t = threadIdx.x;
    const int w = t >> 6, l = t & 63;
    const int wi = w & 1, wj = w >> 1;
    const int l15 = l & 15, lq = l >> 4;
    __shared__ u16 lds[4 * 128 * 64];   // [tile=qk*2+m][row][c(64, swizzled granules)]

    f32x4 acc[2][4][4] = {};

    const int srow = t >> 1, shalf = t & 1;
    for (int bk = 0; bk < 4; ++bk){
        #pragma unroll
        for (int tile = 0; tile < 4; ++tile){     // 0,1 = q(m0,m1); 2,3 = k(m0,m1)
            const int qk = tile >> 1, m = tile & 1;
            const u16* sp = qk ? kB : qB;
            const int row0 = (qk ? jt : it) * 128;
            const u16* g = sp + (size_t)((b*M_ + m)*N_ + row0 + srow) * D_ + bk*64 + shalf*32;
            const uint4* gp = (const uint4*)g;
            uint4 v0 = gp[0], v1 = gp[1], v2 = gp[2], v3 = gp[3];
            u16* base = &lds[(tile*128 + srow) * 64];
            const int rs = srow & 7;
            *(uint4*)&base[((shalf*4 + 0) ^ rs) * 8] = v0;
            *(uint4*)&base[((shalf*4 + 1) ^ rs) * 8] = v1;
            *(uint4*)&base[((shalf*4 + 2) ^ rs) * 8] = v2;
            *(uint4*)&base[((shalf*4 + 3) ^ rs) * 8] = v3;
        }
        __syncthreads();
        #pragma unroll
        for (int ks = 0; ks < 2; ++ks){
            #pragma unroll
            for (int m = 0; m < 2; ++m){
                half8 a[4], bb[4];
                #pragma unroll
                for (int ti = 0; ti < 4; ++ti){
                    const int row = wi*64 + ti*16 + l15;
                    const int gr = (ks*4 + lq) ^ (row & 7);
                    a[ti] = *(const half8*)&lds[(m*128 + row)*64 + gr*8];
                }
                #pragma unroll
                for (int tj = 0; tj < 4; ++tj){
                    const int row = wj*64 + tj*16 + l15;
                    const int gr = (ks*4 + lq) ^ (row & 7);
                    bb[tj] = *(const half8*)&lds[((2 + m)*128 + row)*64 + gr*8];
                }
                #pragma unroll
                for (int ti = 0; ti < 4; ++ti)
                    #pragma unroll
                    for (int tj = 0; tj < 4; ++tj)
                        acc[m][ti][tj] = __builtin_amdgcn_mfma_f32_16x16x32_f16(
                            a[ti], bb[tj], acc[m][ti][tj], 0, 0, 0);
            }
        }
        __syncthreads();
    }

    const float INVT = 0.04419417382415922f;   // 1/sqrt(512)
    uint32_t* op = attnE + (size_t)b * N_ * N_;
    const int ibase = it*128 + wi*64;
    const int jbase = jt*128 + wj*64;
    #pragma unroll
    for (int ti = 0; ti < 4; ++ti){
        float rs[2][4] = {};   // [mixture][rr] partial row sums over this wave's j
        #pragma unroll
        for (int tj = 0; tj < 4; ++tj){
            #pragma unroll
            for (int rr = 0; rr < 4; ++rr){
                const int i = ibase + ti*16 + lq*4 + rr;   // C/D: row=(l>>4)*4+reg
                const int j = jbase + tj*16 + l15;         //      col=l&15
                const float e0 = __expf(acc[0][ti][tj][rr] * INVT);
                const float e1 = __expf(acc[1][ti][tj][rr] * INVT);
                op[(size_t)i * N_ + j] = pk16(e0, e1);
                rs[0][rr] += e0;
                rs[1][rr] += e1;
            }
        }
        #pragma unroll
        for (int m2 = 0; m2 < 2; ++m2){
            #pragma unroll
            for (int rr = 0; rr < 4; ++rr){
                float s = rs[m2][rr];
                s += __shfl_xor(s, 1); s += __shfl_xor(s, 2);
                s += __shfl_xor(s, 4); s += __shfl_xor(s, 8);
                if (l15 == 0)
                    atomicAdd(&wsSum[(size_t)(b*M_ + m2)*N_ + ibase + ti*16 + lq*4 + rr], s);
            }
        }
    }
}

// ============================================================
// K4 v5: 512 threads = 8 waves = 2 rowgroups(32r) x 4 dv-quarters(128dv).
// v chunk [g(4)][dv(512)][8 f16] = 32KB staged in LDS (double-buffered, from
// the contiguous vF slab when available), B-frags = linear b128 reads.
// E + v-regs prefetched one chunk ahead; ONE s_barrier/chunk (lgkm-only
// drain, global prefetches stay in flight); attn fp32 stored in place
// post-barrier (all waves drained their E(c) reads pre-barrier).
// ============================================================
template<bool HASVB>
__global__ __launch_bounds__(512) void k4_pv(const float* __restrict__ vt,
                                             const u16* __restrict__ vF,
                                             const float* __restrict__ wsLog,
                                             const float* __restrict__ wsSum,
                                             uint32_t* __restrict__ attnE,
                                             float* __restrict__ outO){
    const int tile = blockIdx.x, b = blockIdx.y;
    const int i0 = tile * 64;
    const int t = threadIdx.x, l = t & 63, w = t >> 6;
    const int l15 = l & 15, lq = l >> 4;
    const int rg = w >> 2, dvq = w & 3;
    __shared__ u16 vlds[2][16384];     // 2 x 32KB, layout [g][dv][8]

    const float lg0 = wsLog[b*2 + 0], lg1 = wsLog[b*2 + 1];
    const float pi0 = 1.f / (1.f + __expf(lg1 - lg0));
    const float pi1 = 1.f / (1.f + __expf(lg0 - lg1));

    float p0[2], p1[2];
    uint32_t* erow[2];
    #pragma unroll
    for (int rh = 0; rh < 2; ++rh){
        const int row = i0 + rg*32 + rh*16 + l15;
        p0[rh] = pi0 / wsSum[(size_t)(b*M_ + 0)*N_ + row];
        p1[rh] = pi1 / wsSum[(size_t)(b*M_ + 1)*N_ + row];
        erow[rh] = attnE + (size_t)(b*N_ + row) * N_;
    }

    const u16*   vFb  = vF + (size_t)b * 64 * 16384;            // chunk slabs
    const float* vt32 = vt + ((size_t)(b*DV_ + t)) * N_;        // fallback

    uint4  sv[4];     // staged v regs (HASVB)
    float4 rf[8];     // staged v regs (fallback)

    auto loadV = [&](int c){
        if (HASVB){
            const u16* p = vFb + (size_t)c * 16384;
            #pragma unroll
            for (int k = 0; k < 4; ++k)
                sv[k] = *(const uint4*)(p + k*4096 + t*8);
        } else {
            const float4* p = (const float4*)(vt32 + c*32);
            #pragma unroll
            for (int q = 0; q < 8; ++q) rf[q] = p[q];
        }
    };
    auto writeV = [&](int buf){
        if (HASVB){
            #pragma unroll
            for (int k = 0; k < 4; ++k)
                *(uint4*)&vlds[buf][k*4096 + t*8] = sv[k];
        } else {
            #pragma unroll
            for (int g = 0; g < 4; ++g){
                uint4 u;
                u.x = pk16(rf[2*g].x,   rf[2*g].y);
                u.y = pk16(rf[2*g].z,   rf[2*g].w);
                u.z = pk16(rf[2*g+1].x, rf[2*g+1].y);
                u.w = pk16(rf[2*g+1].z, rf[2*g+1].w);
                *(uint4*)&vlds[buf][g*4096 + t*8] = u;
            }
        }
    };
    auto loadE = [&](uint4 (&e)[4], int c){
        #pragma unroll
        for (int rh = 0; rh < 2; ++rh){
            const uint4* p = (const uint4*)(erow[rh] + c*32 + lq*8);
            e[rh*2 + 0] = p[0];
            e[rh*2 + 1] = p[1];
        }
    };

    f32x4 acc[2][8] = {};
    uint4 eA[4], eB[4];

    loadV(0);
    loadE(eA, 0);

    auto body = [&](int c, uint4 (&ec)[4], uint4 (&en)[4]){
        const int cur = c & 1;
        writeV(cur);                       // v(c): regs loaded one iter ago
        if (c + 1 < 64){
            loadV(c + 1);                  // in flight across the barrier
            loadE(en, c + 1);
        }
        float av[16];
        half8 af[2];
        #pragma unroll
        for (int rh = 0; rh < 2; ++rh){
            uint4 u0 = ec[rh*2], u1 = ec[rh*2 + 1];  // drains E(c) (counted vmcnt)
            float* a = av + rh*8;
            a[0] = p0[rh]*h2f_lo(u0.x) + p1[rh]*h2f_hi(u0.x);
            a[1] = p0[rh]*h2f_lo(u0.y) + p1[rh]*h2f_hi(u0.y);
            a[2] = p0[rh]*h2f_lo(u0.z) + p1[rh]*h2f_hi(u0.z);
            a[3] = p0[rh]*h2f_lo(u0.w) + p1[rh]*h2f_hi(u0.w);
            a[4] = p0[rh]*h2f_lo(u1.x) + p1[rh]*h2f_hi(u1.x);
            a[5] = p0[rh]*h2f_lo(u1.y) + p1[rh]*h2f_hi(u1.y);
            a[6] = p0[rh]*h2f_lo(u1.z) + p1[rh]*h2f_hi(u1.z);
            a[7] = p0[rh]*h2f_lo(u1.w) + p1[rh]*h2f_hi(u1.w);
            uint4 ua;
            ua.x = pk16(a[0], a[1]);
            ua.y = pk16(a[2], a[3]);
            ua.z = pk16(a[4], a[5]);
            ua.w = pk16(a[6], a[7]);
            union { uint4 u; half8 h; } cv; cv.u = ua;
            af[rh] = cv.h;
        }
        // ds_writes drained; E(c) consumed by every wave before the barrier.
        asm volatile("s_waitcnt lgkmcnt(0)" ::: "memory");
        __builtin_amdgcn_sched_barrier(0);
        __builtin_amdgcn_s_barrier();
        __builtin_amdgcn_sched_barrier(0);
        if (dvq == 0){   // finalize attn fp32 in place (post-barrier: race-free)
            #pragma unroll
            for (int rh = 0; rh < 2; ++rh){
                float* ap = (float*)(erow[rh] + c*32 + lq*8);
                *(float4*)ap       = make_float4(av[rh*8+0], av[rh*8+1], av[rh*8+2], av[rh*8+3]);
                *(float4*)(ap + 4) = make_float4(av[rh*8+4], av[rh*8+5], av[rh*8+6], av[rh*8+7]);
            }
        }
        const u16* vb = &vlds[cur][lq*4096 + dvq*1024 + l15*8];
        #pragma unroll
        for (int n = 0; n < 8; ++n){
            half8 bv = *(const half8*)(vb + n*128);
            acc[0][n] = __builtin_amdgcn_mfma_f32_16x16x32_f16(af[0], bv, acc[0][n], 0, 0, 0);
            acc[1][n] = __builtin_amdgcn_mfma_f32_16x16x32_f16(af[1], bv, acc[1][n], 0, 0, 0);
        }
    };

    for (int c = 0; c < 64; c += 2){
        body(c,     eA, eB);
        body(c + 1, eB, eA);
    }

    #pragma unroll
    for (int n = 0; n < 8; ++n){
        #pragma unroll
        for (int rh = 0; rh < 2; ++rh){
            #pragma unroll
            for (int rr = 0; rr < 4; ++rr){
                const int i  = i0 + rg*32 + rh*16 + lq*4 + rr;  // C/D: row=(l>>4)*4+reg
                const int dv = dvq*128 + n*16 + l15;            //      col=l&15
                outO[(size_t)(b*N_ + i)*DV_ + dv] = acc[rh][n][rr];
            }
        }
    }
}

// ============================================================
extern "C" void kernel_launch(void* const* d_in, const int* in_sizes, int n_in,
                              void* d_out, int out_size, void* d_ws, size_t ws_size,
                              hipStream_t stream){
    const float* qt  = (const float*)d_in[0];
    const float* kt  = (const float*)d_in[1];
    const float* vt  = (const float*)d_in[2];
    const float* wgt = (const float*)d_in[3];

    float* wsLog = (float*)d_ws;                         // 16 floats
    float* wsBar = (float*)((char*)d_ws + 4096);         // 4096 floats
    float* wsSum = (float*)((char*)d_ws + 65536);        // 32768 floats (128 KiB)

    u16* stage = (u16*)d_out;                            // qB at 0, kB after it
    u16* kB = stage + QB_U16;
    uint32_t* attnE = (uint32_t*)d_out + OUT_FLOATS;     // attn region doubles as E scratch
    float* outO = (float*)d_out;

    const size_t vfBytes = (size_t)B_ * 64 * 16384 * 2;  // 16 MiB
    u16* vF = (ws_size >= (size_t)1048576 + vfBytes)
                  ? (u16*)((char*)d_ws + 1048576) : (u16*)nullptr;

    hipMemsetAsync(d_ws, 0, 262144, stream);             // zero wsLog/wsBar/wsSum

    k0_transpose<<<dim3(32, 8, 16), 256, 0, stream>>>(qt, kt, stage, wsBar);
    if (vF) k0_vconv<<<dim3(4096), 256, 0, stream>>>(vt, vF);
    k2_logits<<<dim3(16), 64, 0, stream>>>(wgt, wsBar, wsLog);
    k3_qk<<<dim3(16, 16, 8), 256, 0, stream>>>(stage, kB, attnE, wsSum);
    if (vF) k4_pv<true ><<<dim3(32, 8), 512, 0, stream>>>(vt, vF, wsLog, wsSum, attnE, outO);
    else    k4_pv<false><<<dim3(32, 8), 512, 0, stream>>>(vt, vF, wsLog, wsSum, attnE, outO);
}

// Round 8
// 324.031 us; speedup vs baseline: 1.0003x; 1.0003x over previous
//
#include <hip/hip_runtime.h>
#include <stdint.h>

typedef unsigned short u16;
typedef float f32x4 __attribute__((ext_vector_type(4)));
typedef _Float16 half8 __attribute__((ext_vector_type(8)));
typedef __fp16 fp16x2 __attribute__((ext_vector_type(2)));

#define B_  8
#define M_  2
#define DK_ 512
#define D_  256
#define N_  2048
#define DV_ 512

#define OUT_FLOATS (B_*N_*DV_)     /* 8388608 */
#define QB_U16     (B_*M_*N_*D_)   /* 8388608 u16 elements = 16 MiB */

// ---- fp16 pack/unpack helpers -------------------------------------------
__device__ __forceinline__ uint32_t pk16(float a, float b){
    fp16x2 h = __builtin_amdgcn_cvt_pkrtz(a, b);      // v_cvt_pkrtz_f16_f32
    return __builtin_bit_cast(uint32_t, h);
}
__device__ __forceinline__ float h2f_lo(uint32_t u){
    return (float)__builtin_bit_cast(_Float16, (unsigned short)(u & 0xffffu));
}
__device__ __forceinline__ float h2f_hi(uint32_t u){
    return (float)__builtin_bit_cast(_Float16, (unsigned short)(u >> 16));
}

// ============================================================
// K0: transpose-convert qt,kt (fp32 [b, m*256+c, i]) -> f16 [ (b*2+m), row, c ]
// staged into the d_out "output" region. Also folds bar-sum (k1).
// ============================================================
__global__ __launch_bounds__(256) void k0_transpose(const float* __restrict__ qt,
                                                    const float* __restrict__ kt,
                                                    u16* __restrict__ dstBase,
                                                    float* __restrict__ wsBar){
    const int it = blockIdx.x, yc = blockIdx.y, z = blockIdx.z;
    const int b = z & 7, src = z >> 3;
    const float* sp = src ? kt : qt;
    u16* dp = dstBase + (size_t)src * QB_U16;
    const int m = yc >> 2;
    const int cbase = (yc & 3) * 64;
    const int i0 = it * 64;
    __shared__ u16 lds[64 * 72];   // [i][c], pad 72 keeps 16B alignment
    const int t = threadIdx.x;
    {
        const int c_loc = t >> 2;
        const int iq = (t & 3) * 16;
        const float* g = sp + (size_t)(b*DK_ + m*D_ + cbase + c_loc) * N_ + i0 + iq;
        float vv[16];
        *(float4*)&vv[0]  = *(const float4*)(g + 0);
        *(float4*)&vv[4]  = *(const float4*)(g + 4);
        *(float4*)&vv[8]  = *(const float4*)(g + 8);
        *(float4*)&vv[12] = *(const float4*)(g + 12);
        #pragma unroll
        for (int e = 0; e < 16; ++e){
            _Float16 hf = (_Float16)vv[e];
            lds[(iq + e)*72 + c_loc] = __builtin_bit_cast(unsigned short, hf);
        }
        if (src == 0){   // folded k1: partial sum over this thread's 16 i
            float s = 0.f;
            #pragma unroll
            for (int e = 0; e < 16; ++e) s += vv[e];
            s += __shfl_xor(s, 1);
            s += __shfl_xor(s, 2);
            if ((t & 3) == 0)
                atomicAdd(&wsBar[b*DK_ + m*D_ + cbase + c_loc], s);
        }
    }
    __syncthreads();
    {
        const int i_loc = t >> 2;
        const int cq = (t & 3) * 16;
        uint4 a  = *(const uint4*)&lds[i_loc*72 + cq];
        uint4 b2 = *(const uint4*)&lds[i_loc*72 + cq + 8];
        u16* o = dp + (size_t)((b*M_ + m)*N_ + i0 + i_loc) * D_ + cbase + cq;
        *(uint4*)o = a;
        *(uint4*)(o + 8) = b2;
    }
}

// ============================================================
// K0v: vt fp32 [b][dv][j] -> vF f16 fragment-tiled:
// vF[b][jc(64)][g(4)][dv(512)][8 f16]  (one 32KB contiguous slab per chunk)
// ============================================================
__global__ __launch_bounds__(256) void k0_vconv(const float* __restrict__ vt,
                                                u16* __restrict__ vF){
    const int idx = blockIdx.x * 256 + threadIdx.x;   // 0 .. 2^20-1
    const int dv = idx & 511;
    const int g  = (idx >> 9) & 3;
    const int jc = (idx >> 11) & 63;
    const int b  = idx >> 17;
    const float* src = vt + ((size_t)(b*DV_ + dv))*N_ + jc*32 + g*8;
    float4 f0 = *(const float4*)src;
    float4 f1 = *(const float4*)(src + 4);
    uint4 o;
    o.x = pk16(f0.x, f0.y);
    o.y = pk16(f0.z, f0.w);
    o.z = pk16(f1.x, f1.y);
    o.w = pk16(f1.z, f1.w);
    *(uint4*)(vF + (size_t)idx * 8) = o;
}

// ============================================================
// K2: logits[b*2+m] = (sum_c weight[m,c] * barSum[b,c]) / N
// ============================================================
__global__ void k2_logits(const float* __restrict__ wgt,
                          const float* __restrict__ bar,
                          float* __restrict__ wsLog){
    const int bm = blockIdx.x;
    const int b = bm >> 1, m = bm & 1;
    const int l = threadIdx.x; // 64
    float s = 0.f;
    #pragma unroll
    for (int k = 0; k < 8; ++k){
        const int c = l + k*64;
        s += wgt[m*DK_ + c] * bar[b*DK_ + c];
    }
    s += __shfl_xor(s, 1); s += __shfl_xor(s, 2); s += __shfl_xor(s, 4);
    s += __shfl_xor(s, 8); s += __shfl_xor(s, 16); s += __shfl_xor(s, 32);
    if (l == 0) wsLog[bm] = s * (1.f / (float)N_);
}

// ============================================================
// K3: S = q·k for both mixtures, E = exp(S/sqrt(512)) packed as f16 pair
// (m0 lo, m1 hi) into the dword that will later hold attn[b,i,j] fp32.
// Epilogue accumulates per-row exp-sums into wsSum via atomics.
// ============================================================
__global__ __launch_bounds__(256, 2) void k3_qk(const u16* __restrict__ qB,
                                                const u16* __restrict__ kB,
                                                uint32_t* __restrict__ attnE,
                                                float* __restrict__ wsSum){
    const int jt = blockIdx.x, it = blockIdx.y, b = blockIdx.z;
    const int t = threadIdx.x;
    const int w = t >> 6, l = t & 63;
    const int wi = w & 1, wj = w >> 1;
    const int l15 = l & 15, lq = l >> 4;
    __shared__ u16 lds[4 * 128 * 64];   // [tile=qk*2+m][row][c(64, swizzled granules)]

    f32x4 acc[2][4][4] = {};

    const int srow = t >> 1, shalf = t & 1;
    for (int bk = 0; bk < 4; ++bk){
        #pragma unroll
        for (int tile = 0; tile < 4; ++tile){     // 0,1 = q(m0,m1); 2,3 = k(m0,m1)
            const int qk = tile >> 1, m = tile & 1;
            const u16* sp = qk ? kB : qB;
            const int row0 = (qk ? jt : it) * 128;
            const u16* g = sp + (size_t)((b*M_ + m)*N_ + row0 + srow) * D_ + bk*64 + shalf*32;
            const uint4* gp = (const uint4*)g;
            uint4 v0 = gp[0], v1 = gp[1], v2 = gp[2], v3 = gp[3];
            u16* base = &lds[(tile*128 + srow) * 64];
            const int rs = srow & 7;
            *(uint4*)&base[((shalf*4 + 0) ^ rs) * 8] = v0;
            *(uint4*)&base[((shalf*4 + 1) ^ rs) * 8] = v1;
            *(uint4*)&base[((shalf*4 + 2) ^ rs) * 8] = v2;
            *(uint4*)&base[((shalf*4 + 3) ^ rs) * 8] = v3;
        }
        __syncthreads();
        #pragma unroll
        for (int ks = 0; ks < 2; ++ks){
            #pragma unroll
            for (int m = 0; m < 2; ++m){
                half8 a[4], bb[4];
                #pragma unroll
                for (int ti = 0; ti < 4; ++ti){
                    const int row = wi*64 + ti*16 + l15;
                    const int gr = (ks*4 + lq) ^ (row & 7);
                    a[ti] = *(const half8*)&lds[(m*128 + row)*64 + gr*8];
                }
                #pragma unroll
                for (int tj = 0; tj < 4; ++tj){
                    const int row = wj*64 + tj*16 + l15;
                    const int gr = (ks*4 + lq) ^ (row & 7);
                    bb[tj] = *(const half8*)&lds[((2 + m)*128 + row)*64 + gr*8];
                }
                #pragma unroll
                for (int ti = 0; ti < 4; ++ti)
                    #pragma unroll
                    for (int tj = 0; tj < 4; ++tj)
                        acc[m][ti][tj] = __builtin_amdgcn_mfma_f32_16x16x32_f16(
                            a[ti], bb[tj], acc[m][ti][tj], 0, 0, 0);
            }
        }
        __syncthreads();
    }

    const float INVT = 0.04419417382415922f;   // 1/sqrt(512)
    uint32_t* op = attnE + (size_t)b * N_ * N_;
    const int ibase = it*128 + wi*64;
    const int jbase = jt*128 + wj*64;
    #pragma unroll
    for (int ti = 0; ti < 4; ++ti){
        float rs[2][4] = {};   // [mixture][rr] partial row sums over this wave's j
        #pragma unroll
        for (int tj = 0; tj < 4; ++tj){
            #pragma unroll
            for (int rr = 0; rr < 4; ++rr){
                const int i = ibase + ti*16 + lq*4 + rr;   // C/D: row=(l>>4)*4+reg
                const int j = jbase + tj*16 + l15;         //      col=l&15
                const float e0 = __expf(acc[0][ti][tj][rr] * INVT);
                const float e1 = __expf(acc[1][ti][tj][rr] * INVT);
                op[(size_t)i * N_ + j] = pk16(e0, e1);
                rs[0][rr] += e0;
                rs[1][rr] += e1;
            }
        }
        #pragma unroll
        for (int m2 = 0; m2 < 2; ++m2){
            #pragma unroll
            for (int rr = 0; rr < 4; ++rr){
                float s = rs[m2][rr];
                s += __shfl_xor(s, 1); s += __shfl_xor(s, 2);
                s += __shfl_xor(s, 4); s += __shfl_xor(s, 8);
                if (l15 == 0)
                    atomicAdd(&wsSum[(size_t)(b*M_ + m2)*N_ + ibase + ti*16 + lq*4 + rr], s);
            }
        }
    }
}

// ============================================================
// K4 v5: 512 threads = 8 waves = 2 rowgroups(32r) x 4 dv-quarters(128dv).
// v chunk [g(4)][dv(512)][8 f16] = 32KB staged in LDS (double-buffered, from
// the contiguous vF slab when available), B-frags = linear b128 reads.
// E + v-regs prefetched one chunk ahead; ONE s_barrier/chunk (lgkm-only
// drain, global prefetches stay in flight); attn fp32 stored in place
// post-barrier (all waves drained their E(c) reads pre-barrier).
// ============================================================
template<bool HASVB>
__global__ __launch_bounds__(512) void k4_pv(const float* __restrict__ vt,
                                             const u16* __restrict__ vF,
                                             const float* __restrict__ wsLog,
                                             const float* __restrict__ wsSum,
                                             uint32_t* __restrict__ attnE,
                                             float* __restrict__ outO){
    const int tile = blockIdx.x, b = blockIdx.y;
    const int i0 = tile * 64;
    const int t = threadIdx.x, l = t & 63, w = t >> 6;
    const int l15 = l & 15, lq = l >> 4;
    const int rg = w >> 2, dvq = w & 3;
    __shared__ u16 vlds[2][16384];     // 2 x 32KB, layout [g][dv][8]

    const float lg0 = wsLog[b*2 + 0], lg1 = wsLog[b*2 + 1];
    const float pi0 = 1.f / (1.f + __expf(lg1 - lg0));
    const float pi1 = 1.f / (1.f + __expf(lg0 - lg1));

    float p0[2], p1[2];
    uint32_t* erow[2];
    #pragma unroll
    for (int rh = 0; rh < 2; ++rh){
        const int row = i0 + rg*32 + rh*16 + l15;
        p0[rh] = pi0 / wsSum[(size_t)(b*M_ + 0)*N_ + row];
        p1[rh] = pi1 / wsSum[(size_t)(b*M_ + 1)*N_ + row];
        erow[rh] = attnE + (size_t)(b*N_ + row) * N_;
    }

    const u16*   vFb  = vF + (size_t)b * 64 * 16384;            // chunk slabs
    const float* vt32 = vt + ((size_t)(b*DV_ + t)) * N_;        // fallback

    uint4  sv[4];     // staged v regs (HASVB)
    float4 rf[8];     // staged v regs (fallback)

    auto loadV = [&](int c){
        if (HASVB){
            const u16* p = vFb + (size_t)c * 16384;
            #pragma unroll
            for (int k = 0; k < 4; ++k)
                sv[k] = *(const uint4*)(p + k*4096 + t*8);
        } else {
            const float4* p = (const float4*)(vt32 + c*32);
            #pragma unroll
            for (int q = 0; q < 8; ++q) rf[q] = p[q];
        }
    };
    auto writeV = [&](int buf){
        if (HASVB){
            #pragma unroll
            for (int k = 0; k < 4; ++k)
                *(uint4*)&vlds[buf][k*4096 + t*8] = sv[k];
        } else {
            #pragma unroll
            for (int g = 0; g < 4; ++g){
                uint4 u;
                u.x = pk16(rf[2*g].x,   rf[2*g].y);
                u.y = pk16(rf[2*g].z,   rf[2*g].w);
                u.z = pk16(rf[2*g+1].x, rf[2*g+1].y);
                u.w = pk16(rf[2*g+1].z, rf[2*g+1].w);
                *(uint4*)&vlds[buf][g*4096 + t*8] = u;
            }
        }
    };
    auto loadE = [&](uint4 (&e)[4], int c){
        #pragma unroll
        for (int rh = 0; rh < 2; ++rh){
            const uint4* p = (const uint4*)(erow[rh] + c*32 + lq*8);
            e[rh*2 + 0] = p[0];
            e[rh*2 + 1] = p[1];
        }
    };

    f32x4 acc[2][8] = {};
    uint4 eA[4], eB[4];

    loadV(0);
    loadE(eA, 0);

    auto body = [&](int c, uint4 (&ec)[4], uint4 (&en)[4]){
        const int cur = c & 1;
        writeV(cur);                       // v(c): regs loaded one iter ago
        if (c + 1 < 64){
            loadV(c + 1);                  // in flight across the barrier
            loadE(en, c + 1);
        }
        float av[16];
        half8 af[2];
        #pragma unroll
        for (int rh = 0; rh < 2; ++rh){
            uint4 u0 = ec[rh*2], u1 = ec[rh*2 + 1];  // drains E(c) (counted vmcnt)
            float* a = av + rh*8;
            a[0] = p0[rh]*h2f_lo(u0.x) + p1[rh]*h2f_hi(u0.x);
            a[1] = p0[rh]*h2f_lo(u0.y) + p1[rh]*h2f_hi(u0.y);
            a[2] = p0[rh]*h2f_lo(u0.z) + p1[rh]*h2f_hi(u0.z);
            a[3] = p0[rh]*h2f_lo(u0.w) + p1[rh]*h2f_hi(u0.w);
            a[4] = p0[rh]*h2f_lo(u1.x) + p1[rh]*h2f_hi(u1.x);
            a[5] = p0[rh]*h2f_lo(u1.y) + p1[rh]*h2f_hi(u1.y);
            a[6] = p0[rh]*h2f_lo(u1.z) + p1[rh]*h2f_hi(u1.z);
            a[7] = p0[rh]*h2f_lo(u1.w) + p1[rh]*h2f_hi(u1.w);
            uint4 ua;
            ua.x = pk16(a[0], a[1]);
            ua.y = pk16(a[2], a[3]);
            ua.z = pk16(a[4], a[5]);
            ua.w = pk16(a[6], a[7]);
            union { uint4 u; half8 h; } cv; cv.u = ua;
            af[rh] = cv.h;
        }
        // ds_writes drained; E(c) consumed by every wave before the barrier.
        asm volatile("s_waitcnt lgkmcnt(0)" ::: "memory");
        __builtin_amdgcn_sched_barrier(0);
        __builtin_amdgcn_s_barrier();
        __builtin_amdgcn_sched_barrier(0);
        if (dvq == 0){   // finalize attn fp32 in place (post-barrier: race-free)
            #pragma unroll
            for (int rh = 0; rh < 2; ++rh){
                float* ap = (float*)(erow[rh] + c*32 + lq*8);
                *(float4*)ap       = make_float4(av[rh*8+0], av[rh*8+1], av[rh*8+2], av[rh*8+3]);
                *(float4*)(ap + 4) = make_float4(av[rh*8+4], av[rh*8+5], av[rh*8+6], av[rh*8+7]);
            }
        }
        const u16* vb = &vlds[cur][lq*4096 + dvq*1024 + l15*8];
        #pragma unroll
        for (int n = 0; n < 8; ++n){
            half8 bv = *(const half8*)(vb + n*128);
            acc[0][n] = __builtin_amdgcn_mfma_f32_16x16x32_f16(af[0], bv, acc[0][n], 0, 0, 0);
            acc[1][n] = __builtin_amdgcn_mfma_f32_16x16x32_f16(af[1], bv, acc[1][n], 0, 0, 0);
        }
    };

    for (int c = 0; c < 64; c += 2){
        body(c,     eA, eB);
        body(c + 1, eB, eA);
    }

    #pragma unroll
    for (int n = 0; n < 8; ++n){
        #pragma unroll
        for (int rh = 0; rh < 2; ++rh){
            #pragma unroll
            for (int rr = 0; rr < 4; ++rr){
                const int i  = i0 + rg*32 + rh*16 + lq*4 + rr;  // C/D: row=(l>>4)*4+reg
                const int dv = dvq*128 + n*16 + l15;            //      col=l&15
                outO[(size_t)(b*N_ + i)*DV_ + dv] = acc[rh][n][rr];
            }
        }
    }
}

// ============================================================
extern "C" void kernel_launch(void* const* d_in, const int* in_sizes, int n_in,
                              void* d_out, int out_size, void* d_ws, size_t ws_size,
                              hipStream_t stream){
    const float* qt  = (const float*)d_in[0];
    const float* kt  = (const float*)d_in[1];
    const float* vt  = (const float*)d_in[2];
    const float* wgt = (const float*)d_in[3];

    float* wsLog = (float*)d_ws;                         // 16 floats
    float* wsBar = (float*)((char*)d_ws + 4096);         // 4096 floats
    float* wsSum = (float*)((char*)d_ws + 65536);        // 32768 floats (128 KiB)

    u16* stage = (u16*)d_out;                            // qB at 0, kB after it
    u16* kB = stage + QB_U16;
    uint32_t* attnE = (uint32_t*)d_out + OUT_FLOATS;     // attn region doubles as E scratch
    float* outO = (float*)d_out;

    const size_t vfBytes = (size_t)B_ * 64 * 16384 * 2;  // 16 MiB
    u16* vF = (ws_size >= (size_t)1048576 + vfBytes)
                  ? (u16*)((char*)d_ws + 1048576) : (u16*)nullptr;

    hipMemsetAsync(d_ws, 0, 262144, stream);             // zero wsLog/wsBar/wsSum

    k0_transpose<<<dim3(32, 8, 16), 256, 0, stream>>>(qt, kt, stage, wsBar);
    if (vF) k0_vconv<<<dim3(4096), 256, 0, stream>>>(vt, vF);
    k2_logits<<<dim3(16), 64, 0, stream>>>(wgt, wsBar, wsLog);
    k3_qk<<<dim3(16, 16, 8), 256, 0, stream>>>(stage, kB, attnE, wsSum);
    if (vF) k4_pv<true ><<<dim3(32, 8), 512, 0, stream>>>(vt, vF, wsLog, wsSum, attnE, outO);
    else    k4_pv<false><<<dim3(32, 8), 512, 0, stream>>>(vt, vF, wsLog, wsSum, attnE, outO);
}

// Round 9
// 250.935 us; speedup vs baseline: 1.2917x; 1.2913x over previous
//
#include <hip/hip_runtime.h>
#include <stdint.h>

typedef unsigned short u16;
typedef float f32x4 __attribute__((ext_vector_type(4)));
typedef _Float16 half8 __attribute__((ext_vector_type(8)));
typedef __fp16 fp16x2 __attribute__((ext_vector_type(2)));

#define B_  8
#define M_  2
#define DK_ 512
#define D_  256
#define N_  2048
#define DV_ 512

#define OUT_FLOATS (B_*N_*DV_)     /* 8388608 */
#define QB_U16     (B_*M_*N_*D_)   /* 8388608 u16 elements = 16 MiB */

// ---- fp16 pack/unpack helpers -------------------------------------------
__device__ __forceinline__ uint32_t pk16(float a, float b){
    fp16x2 h = __builtin_amdgcn_cvt_pkrtz(a, b);      // v_cvt_pkrtz_f16_f32
    return __builtin_bit_cast(uint32_t, h);
}
__device__ __forceinline__ float h2f_lo(uint32_t u){
    return (float)__builtin_bit_cast(_Float16, (unsigned short)(u & 0xffffu));
}
__device__ __forceinline__ float h2f_hi(uint32_t u){
    return (float)__builtin_bit_cast(_Float16, (unsigned short)(u >> 16));
}

// ============================================================
// K0: transpose-convert qt,kt (fp32 [b, m*256+c, i]) -> f16 [ (b*2+m), row, c ]
// staged into the d_out "output" region. Also folds bar-sum (k1).
// ============================================================
__global__ __launch_bounds__(256) void k0_transpose(const float* __restrict__ qt,
                                                    const float* __restrict__ kt,
                                                    u16* __restrict__ dstBase,
                                                    float* __restrict__ wsBar){
    const int it = blockIdx.x, yc = blockIdx.y, z = blockIdx.z;
    const int b = z & 7, src = z >> 3;
    const float* sp = src ? kt : qt;
    u16* dp = dstBase + (size_t)src * QB_U16;
    const int m = yc >> 2;
    const int cbase = (yc & 3) * 64;
    const int i0 = it * 64;
    __shared__ u16 lds[64 * 72];   // [i][c], pad 72 keeps 16B alignment
    const int t = threadIdx.x;
    {
        const int c_loc = t >> 2;
        const int iq = (t & 3) * 16;
        const float* g = sp + (size_t)(b*DK_ + m*D_ + cbase + c_loc) * N_ + i0 + iq;
        float vv[16];
        *(float4*)&vv[0]  = *(const float4*)(g + 0);
        *(float4*)&vv[4]  = *(const float4*)(g + 4);
        *(float4*)&vv[8]  = *(const float4*)(g + 8);
        *(float4*)&vv[12] = *(const float4*)(g + 12);
        #pragma unroll
        for (int e = 0; e < 16; ++e){
            _Float16 hf = (_Float16)vv[e];
            lds[(iq + e)*72 + c_loc] = __builtin_bit_cast(unsigned short, hf);
        }
        if (src == 0){   // folded k1: partial sum over this thread's 16 i
            float s = 0.f;
            #pragma unroll
            for (int e = 0; e < 16; ++e) s += vv[e];
            s += __shfl_xor(s, 1);
            s += __shfl_xor(s, 2);
            if ((t & 3) == 0)
                atomicAdd(&wsBar[b*DK_ + m*D_ + cbase + c_loc], s);
        }
    }
    __syncthreads();
    {
        const int i_loc = t >> 2;
        const int cq = (t & 3) * 16;
        uint4 a  = *(const uint4*)&lds[i_loc*72 + cq];
        uint4 b2 = *(const uint4*)&lds[i_loc*72 + cq + 8];
        u16* o = dp + (size_t)((b*M_ + m)*N_ + i0 + i_loc) * D_ + cbase + cq;
        *(uint4*)o = a;
        *(uint4*)(o + 8) = b2;
    }
}

// ============================================================
// K0v: vt fp32 [b][dv][j] -> vF f16 fragment-tiled:
// vF[b][jc(64)][g(4)][dv(512)][8 f16]  (one 32KB contiguous slab per chunk)
// ============================================================
__global__ __launch_bounds__(256) void k0_vconv(const float* __restrict__ vt,
                                                u16* __restrict__ vF){
    const int idx = blockIdx.x * 256 + threadIdx.x;   // 0 .. 2^20-1
    const int dv = idx & 511;
    const int g  = (idx >> 9) & 3;
    const int jc = (idx >> 11) & 63;
    const int b  = idx >> 17;
    const float* src = vt + ((size_t)(b*DV_ + dv))*N_ + jc*32 + g*8;
    float4 f0 = *(const float4*)src;
    float4 f1 = *(const float4*)(src + 4);
    uint4 o;
    o.x = pk16(f0.x, f0.y);
    o.y = pk16(f0.z, f0.w);
    o.z = pk16(f1.x, f1.y);
    o.w = pk16(f1.z, f1.w);
    *(uint4*)(vF + (size_t)idx * 8) = o;
}

// ============================================================
// K2: logits[b*2+m] = (sum_c weight[m,c] * barSum[b,c]) / N
// ============================================================
__global__ void k2_logits(const float* __restrict__ wgt,
                          const float* __restrict__ bar,
                          float* __restrict__ wsLog){
    const int bm = blockIdx.x;
    const int b = bm >> 1, m = bm & 1;
    const int l = threadIdx.x; // 64
    float s = 0.f;
    #pragma unroll
    for (int k = 0; k < 8; ++k){
        const int c = l + k*64;
        s += wgt[m*DK_ + c] * bar[b*DK_ + c];
    }
    s += __shfl_xor(s, 1); s += __shfl_xor(s, 2); s += __shfl_xor(s, 4);
    s += __shfl_xor(s, 8); s += __shfl_xor(s, 16); s += __shfl_xor(s, 32);
    if (l == 0) wsLog[bm] = s * (1.f / (float)N_);
}

// ============================================================
// K3: S = q·k for both mixtures, E = exp(S/sqrt(512)) packed as f16 pair
// (m0 lo, m1 hi) into the dword that will later hold attn[b,i,j] fp32.
// Epilogue accumulates per-row exp-sums into wsSum via atomics.
// ============================================================
__global__ __launch_bounds__(256, 2) void k3_qk(const u16* __restrict__ qB,
                                                const u16* __restrict__ kB,
                                                uint32_t* __restrict__ attnE,
                                                float* __restrict__ wsSum){
    const int jt = blockIdx.x, it = blockIdx.y, b = blockIdx.z;
    const int t = threadIdx.x;
    const int w = t >> 6, l = t & 63;
    const int wi = w & 1, wj = w >> 1;
    const int l15 = l & 15, lq = l >> 4;
    __shared__ u16 lds[4 * 128 * 64];   // [tile=qk*2+m][row][c(64, swizzled granules)]

    f32x4 acc[2][4][4] = {};

    const int srow = t >> 1, shalf = t & 1;
    for (int bk = 0; bk < 4; ++bk){
        #pragma unroll
        for (int tile = 0; tile < 4; ++tile){     // 0,1 = q(m0,m1); 2,3 = k(m0,m1)
            const int qk = tile >> 1, m = tile & 1;
            const u16* sp = qk ? kB : qB;
            const int row0 = (qk ? jt : it) * 128;
            const u16* g = sp + (size_t)((b*M_ + m)*N_ + row0 + srow) * D_ + bk*64 + shalf*32;
            const uint4* gp = (const uint4*)g;
            uint4 v0 = gp[0], v1 = gp[1], v2 = gp[2], v3 = gp[3];
            u16* base = &lds[(tile*128 + srow) * 64];
            const int rs = srow & 7;
            *(uint4*)&base[((shalf*4 + 0) ^ rs) * 8] = v0;
            *(uint4*)&base[((shalf*4 + 1) ^ rs) * 8] = v1;
            *(uint4*)&base[((shalf*4 + 2) ^ rs) * 8] = v2;
            *(uint4*)&base[((shalf*4 + 3) ^ rs) * 8] = v3;
        }
        __syncthreads();
        #pragma unroll
        for (int ks = 0; ks < 2; ++ks){
            #pragma unroll
            for (int m = 0; m < 2; ++m){
                half8 a[4], bb[4];
                #pragma unroll
                for (int ti = 0; ti < 4; ++ti){
                    const int row = wi*64 + ti*16 + l15;
                    const int gr = (ks*4 + lq) ^ (row & 7);
                    a[ti] = *(const half8*)&lds[(m*128 + row)*64 + gr*8];
                }
                #pragma unroll
                for (int tj = 0; tj < 4; ++tj){
                    const int row = wj*64 + tj*16 + l15;
                    const int gr = (ks*4 + lq) ^ (row & 7);
                    bb[tj] = *(const half8*)&lds[((2 + m)*128 + row)*64 + gr*8];
                }
                #pragma unroll
                for (int ti = 0; ti < 4; ++ti)
                    #pragma unroll
                    for (int tj = 0; tj < 4; ++tj)
                        acc[m][ti][tj] = __builtin_amdgcn_mfma_f32_16x16x32_f16(
                            a[ti], bb[tj], acc[m][ti][tj], 0, 0, 0);
            }
        }
        __syncthreads();
    }

    const float INVT = 0.04419417382415922f;   // 1/sqrt(512)
    uint32_t* op = attnE + (size_t)b * N_ * N_;
    const int ibase = it*128 + wi*64;
    const int jbase = jt*128 + wj*64;
    #pragma unroll
    for (int ti = 0; ti < 4; ++ti){
        float rs[2][4] = {};   // [mixture][rr] partial row sums over this wave's j
        #pragma unroll
        for (int tj = 0; tj < 4; ++tj){
            #pragma unroll
            for (int rr = 0; rr < 4; ++rr){
                const int i = ibase + ti*16 + lq*4 + rr;   // C/D: row=(l>>4)*4+reg
                const int j = jbase + tj*16 + l15;         //      col=l&15
                const float e0 = __expf(acc[0][ti][tj][rr] * INVT);
                const float e1 = __expf(acc[1][ti][tj][rr] * INVT);
                op[(size_t)i * N_ + j] = pk16(e0, e1);
                rs[0][rr] += e0;
                rs[1][rr] += e1;
            }
        }
        #pragma unroll
        for (int m2 = 0; m2 < 2; ++m2){
            #pragma unroll
            for (int rr = 0; rr < 4; ++rr){
                float s = rs[m2][rr];
                s += __shfl_xor(s, 1); s += __shfl_xor(s, 2);
                s += __shfl_xor(s, 4); s += __shfl_xor(s, 8);
                if (l15 == 0)
                    atomicAdd(&wsSum[(size_t)(b*M_ + m2)*N_ + ibase + ti*16 + lq*4 + rr], s);
            }
        }
    }
}

// ============================================================
// K4 v6: 512 threads = 8 waves = 2 rowgroups(32r) x 4 dv-quarters(128dv),
// 64 rows/block, grid (32,8). ALL global accesses lane-contiguous:
//  - v from vF slab (contiguous 32KB/chunk) -> linear LDS (r8 layout, 0-confl)
//  - E read COALESCED (1 uint4/thread, 8 lanes/row) into XOR-swizzled LDS
//    tile; A-fragments read from LDS (2-way, free)
//  - attn fp32 built in LDS tile (fragment writes), stored COALESCED one
//    chunk deferred
// One __syncthreads()/chunk; everything prefetched one chunk ahead; plain
// compiler-scheduled waits (no raw barriers).
// ============================================================
template<bool HASVB>
__global__ __launch_bounds__(512) void k4_pv(const float* __restrict__ vt,
                                             const u16* __restrict__ vF,
                                             const float* __restrict__ wsLog,
                                             const float* __restrict__ wsSum,
                                             uint32_t* __restrict__ attnE,
                                             float* __restrict__ outO){
    const int tile = blockIdx.x, b = blockIdx.y;
    const int i0 = tile * 64;
    const int t = threadIdx.x, l = t & 63, w = t >> 6;
    const int l15 = l & 15, lq = l >> 4;
    const int rg = w >> 2, dvq = w & 3;
    __shared__ u16      vbuf[2][16384];   // 64 KB: v chunk [g(4)][dv(512)][8]
    __shared__ uint32_t ebuf[2][2048];    // 16 KB: E chunk [row(64)][g(8)^sw][4]
    __shared__ float    abuf[2][2048];    // 16 KB: attn chunk, same layout

    const float lg0 = wsLog[b*2 + 0], lg1 = wsLog[b*2 + 1];
    const float pi0 = 1.f / (1.f + __expf(lg1 - lg0));
    const float pi1 = 1.f / (1.f + __expf(lg0 - lg1));

    float p0[2], p1[2];
    #pragma unroll
    for (int rh = 0; rh < 2; ++rh){
        const int row = i0 + rg*32 + rh*16 + l15;
        p0[rh] = pi0 / wsSum[(size_t)(b*M_ + 0)*N_ + row];
        p1[rh] = pi1 / wsSum[(size_t)(b*M_ + 1)*N_ + row];
    }

    // coalesced E/attn mapping: thread t <-> (row = t>>3, granule = t&7)
    const int crow = t >> 3, cg = t & 7, cgs = cg ^ (crow & 7);
    const uint32_t* egl = attnE + (size_t)(b*N_ + i0 + crow)*N_ + cg*4;
    float*          agl = (float*)attnE + (size_t)(b*N_ + i0 + crow)*N_ + cg*4;

    const u16*   vFb  = vF + (size_t)b * 64 * 16384;
    const float* vt32 = vt + (size_t)(b*DV_ + t)*N_;

    uint4  sv[4];
    float4 rf[8];
    uint4  er;

    auto loadV = [&](int c){
        if (HASVB){
            const u16* p = vFb + (size_t)c * 16384;
            #pragma unroll
            for (int k = 0; k < 4; ++k)
                sv[k] = *(const uint4*)(p + k*4096 + t*8);
        } else {
            const float4* p = (const float4*)(vt32 + c*32);
            #pragma unroll
            for (int q = 0; q < 8; ++q) rf[q] = p[q];
        }
    };
    auto writeV = [&](int buf){
        if (HASVB){
            #pragma unroll
            for (int k = 0; k < 4; ++k)
                *(uint4*)&vbuf[buf][k*4096 + t*8] = sv[k];
        } else {
            #pragma unroll
            for (int g = 0; g < 4; ++g){
                uint4 u;
                u.x = pk16(rf[2*g].x,   rf[2*g].y);
                u.y = pk16(rf[2*g].z,   rf[2*g].w);
                u.z = pk16(rf[2*g+1].x, rf[2*g+1].y);
                u.w = pk16(rf[2*g+1].z, rf[2*g+1].w);
                *(uint4*)&vbuf[buf][g*4096 + t*8] = u;
            }
        }
    };
    auto loadE  = [&](int c){ er = *(const uint4*)(egl + c*32); };
    auto writeE = [&](int buf){ *(uint4*)&ebuf[buf][crow*32 + cgs*4] = er; };

    f32x4 acc[2][8] = {};

    // prologue: chunk 0 staged, chunk 1 in regs
    loadV(0); loadE(0);
    writeV(0); writeE(0);
    loadV(1); loadE(1);
    __syncthreads();

    for (int c = 0; c < 64; ++c){
        const int cur = c & 1;
        // A-fragment reads for chunk c (2-way banked, free)
        uint4 ef0[2], ef1[2];
        int gsa[2], gsb[2], rr_[2];
        #pragma unroll
        for (int rh = 0; rh < 2; ++rh){
            const int r = rg*32 + rh*16 + l15;
            gsa[rh] = (lq*2)     ^ (r & 7);
            gsb[rh] = (lq*2 + 1) ^ (r & 7);
            rr_[rh] = r;
            ef0[rh] = *(const uint4*)&ebuf[cur][r*32 + gsa[rh]*4];
            ef1[rh] = *(const uint4*)&ebuf[cur][r*32 + gsb[rh]*4];
        }
        if (c + 1 < 64){ writeV(cur ^ 1); writeE(cur ^ 1); }   // from regs
        if (c + 2 < 64){ loadV(c + 2); loadE(c + 2); }         // stay in flight

        float av[2][8];
        half8 af[2];
        #pragma unroll
        for (int rh = 0; rh < 2; ++rh){
            const uint4 u0 = ef0[rh], u1 = ef1[rh];
            av[rh][0] = p0[rh]*h2f_lo(u0.x) + p1[rh]*h2f_hi(u0.x);
            av[rh][1] = p0[rh]*h2f_lo(u0.y) + p1[rh]*h2f_hi(u0.y);
            av[rh][2] = p0[rh]*h2f_lo(u0.z) + p1[rh]*h2f_hi(u0.z);
            av[rh][3] = p0[rh]*h2f_lo(u0.w) + p1[rh]*h2f_hi(u0.w);
            av[rh][4] = p0[rh]*h2f_lo(u1.x) + p1[rh]*h2f_hi(u1.x);
            av[rh][5] = p0[rh]*h2f_lo(u1.y) + p1[rh]*h2f_hi(u1.y);
            av[rh][6] = p0[rh]*h2f_lo(u1.z) + p1[rh]*h2f_hi(u1.z);
            av[rh][7] = p0[rh]*h2f_lo(u1.w) + p1[rh]*h2f_hi(u1.w);
            uint4 ua;
            ua.x = pk16(av[rh][0], av[rh][1]);
            ua.y = pk16(av[rh][2], av[rh][3]);
            ua.z = pk16(av[rh][4], av[rh][5]);
            ua.w = pk16(av[rh][6], av[rh][7]);
            union { uint4 u; half8 h; } cv; cv.u = ua;
            af[rh] = cv.h;
        }
        if (dvq == 0){   // fragment-pattern attn writes into abuf[cur]
            #pragma unroll
            for (int rh = 0; rh < 2; ++rh){
                *(float4*)&abuf[cur][rr_[rh]*32 + gsa[rh]*4] =
                    make_float4(av[rh][0], av[rh][1], av[rh][2], av[rh][3]);
                *(float4*)&abuf[cur][rr_[rh]*32 + gsb[rh]*4] =
                    make_float4(av[rh][4], av[rh][5], av[rh][6], av[rh][7]);
            }
        }
        if (c >= 1){     // coalesced store of attn chunk c-1 (full 64B lines)
            float4 a = *(const float4*)&abuf[cur ^ 1][crow*32 + cgs*4];
            *(float4*)(agl + (c - 1)*32) = a;
        }
        // PV MFMAs on chunk c (vbuf[cur] written last interval)
        const u16* vb = &vbuf[cur][lq*4096 + dvq*1024 + l15*8];
        #pragma unroll
        for (int n = 0; n < 8; ++n){
            half8 bv = *(const half8*)(vb + n*128);
            acc[0][n] = __builtin_amdgcn_mfma_f32_16x16x32_f16(af[0], bv, acc[0][n], 0, 0, 0);
            acc[1][n] = __builtin_amdgcn_mfma_f32_16x16x32_f16(af[1], bv, acc[1][n], 0, 0, 0);
        }
        __syncthreads();
    }
    {   // epilogue: store attn chunk 63
        float4 a = *(const float4*)&abuf[1][crow*32 + cgs*4];
        *(float4*)(agl + 63*32) = a;
    }

    #pragma unroll
    for (int n = 0; n < 8; ++n){
        #pragma unroll
        for (int rh = 0; rh < 2; ++rh){
            #pragma unroll
            for (int rr = 0; rr < 4; ++rr){
                const int i  = i0 + rg*32 + rh*16 + lq*4 + rr;  // C/D: row=(l>>4)*4+reg
                const int dv = dvq*128 + n*16 + l15;            //      col=l&15
                outO[(size_t)(b*N_ + i)*DV_ + dv] = acc[rh][n][rr];
            }
        }
    }
}

// ============================================================
extern "C" void kernel_launch(void* const* d_in, const int* in_sizes, int n_in,
                              void* d_out, int out_size, void* d_ws, size_t ws_size,
                              hipStream_t stream){
    const float* qt  = (const float*)d_in[0];
    const float* kt  = (const float*)d_in[1];
    const float* vt  = (const float*)d_in[2];
    const float* wgt = (const float*)d_in[3];

    float* wsLog = (float*)d_ws;                         // 16 floats
    float* wsBar = (float*)((char*)d_ws + 4096);         // 4096 floats
    float* wsSum = (float*)((char*)d_ws + 65536);        // 32768 floats (128 KiB)

    u16* stage = (u16*)d_out;                            // qB at 0, kB after it
    u16* kB = stage + QB_U16;
    uint32_t* attnE = (uint32_t*)d_out + OUT_FLOATS;     // attn region doubles as E scratch
    float* outO = (float*)d_out;

    const size_t vfBytes = (size_t)B_ * 64 * 16384 * 2;  // 16 MiB
    u16* vF = (ws_size >= (size_t)1048576 + vfBytes)
                  ? (u16*)((char*)d_ws + 1048576) : (u16*)nullptr;

    hipMemsetAsync(d_ws, 0, 262144, stream);             // zero wsLog/wsBar/wsSum

    k0_transpose<<<dim3(32, 8, 16), 256, 0, stream>>>(qt, kt, stage, wsBar);
    if (vF) k0_vconv<<<dim3(4096), 256, 0, stream>>>(vt, vF);
    k2_logits<<<dim3(16), 64, 0, stream>>>(wgt, wsBar, wsLog);
    k3_qk<<<dim3(16, 16, 8), 256, 0, stream>>>(stage, kB, attnE, wsSum);
    if (vF) k4_pv<true ><<<dim3(32, 8), 512, 0, stream>>>(vt, vF, wsLog, wsSum, attnE, outO);
    else    k4_pv<false><<<dim3(32, 8), 512, 0, stream>>>(vt, vF, wsLog, wsSum, attnE, outO);
}